// Round 2
// baseline (42332.336 us; speedup 1.0000x reference)
//
#include <hip/hip_runtime.h>
#include <hip/hip_bf16.h>

// SimpleLSTM B=256, T=512, I=3, H=512. out = fc(h_T).
// MFMA split-bf16 version: per step, gates = h @ W_hh^T computed as
//   h_hi@W_hi + h_hi@W_lo + h_lo@W_hi   (bf16 inputs, fp32 accum)
// 256 wgs x 512 thr. wg (bb=wg&7, hb=wg>>3): batches bb*32..+31, hidden hb*16..+15
// => 64 gate rows (4 quadrants x 16). W slice in LDS (bf16 hi+lo, 128 KB, XOR-swizzled).
// h double-buffered in ws (bf16 hi+lo). One 32-wg atomic barrier per step.

#define Hh   512
#define Bsz  256
#define Tt   512

#define NGRP 8      // batch groups (mapped to XCDs via wg&7)
#define MB   32     // batches per group
#define HS   16     // hidden per wg
#define NROW 64     // gate rows per wg (4 quadrants x 16)
#define NTHR 512
#define NWG  256

typedef float  f32x4 __attribute__((ext_vector_type(4)));
typedef short  s16x8 __attribute__((ext_vector_type(8)));

// ws layout (bytes)
#define HHI_OFF 0
#define HHI_SZ  (2 * Bsz * Hh * 2)          // 512 KB: [2][256][512] bf16
#define HLO_OFF (HHI_OFF + HHI_SZ)
#define HLO_SZ  (2 * Bsz * Hh * 2)
#define BAR_OFF (HLO_OFF + HLO_SZ)          // 8 counters, stride 16 uints
#define CTRL_UINTS 256

__device__ __forceinline__ float sigm(float v)  { return 1.0f / (1.0f + __expf(-v)); }
__device__ __forceinline__ float tanhx(float v) { return 2.0f / (1.0f + __expf(-2.0f * v)) - 1.0f; }

__device__ __forceinline__ ushort f2bf(float f) {   // round-to-nearest-even
  unsigned u = __float_as_uint(f);
  return (ushort)((u + 0x7FFFu + ((u >> 16) & 1u)) >> 16);
}
__device__ __forceinline__ float bf2f(ushort u) {
  return __uint_as_float((unsigned)u << 16);
}

__device__ __forceinline__ void group_barrier(unsigned* bar, int tid, unsigned target) {
  __threadfence();
  __syncthreads();
  if (tid == 0) {
    __hip_atomic_fetch_add(bar, 1u, __ATOMIC_RELEASE, __HIP_MEMORY_SCOPE_AGENT);
    while (__hip_atomic_load(bar, __ATOMIC_ACQUIRE, __HIP_MEMORY_SCOPE_AGENT) < target)
      __builtin_amdgcn_s_sleep(1);
  }
  __syncthreads();
  __threadfence();
}

__global__ void init_ws(unsigned* ctrl) {
  ctrl[threadIdx.x] = 0u;
}

__global__ __launch_bounds__(NTHR, 1)
void lstm_kernel(const float* __restrict__ x,   const float* __restrict__ Wih,
                 const float* __restrict__ Whh, const float* __restrict__ bih,
                 const float* __restrict__ bhh, const float* __restrict__ fcw,
                 const float* __restrict__ fcb, float* __restrict__ out,
                 char* __restrict__ ws)
{
  const int tid = threadIdx.x;
  const int wg  = blockIdx.x;
  const int bb  = wg & 7;       // batch group -> XCD-affine
  const int hb  = wg >> 3;      // 0..31
  const int j0  = hb * HS;
  const int b0  = bb * MB;

  ushort*   hhi = (ushort*)(ws + HHI_OFF);
  ushort*   hlo = (ushort*)(ws + HLO_OFF);
  unsigned* bar = (unsigned*)(ws + BAR_OFF) + bb * 16;

  __shared__ ushort whi[NROW * Hh];          // 64 KB, XOR-swizzled rows
  __shared__ ushort wlo[NROW * Hh];          // 64 KB
  __shared__ float  gates_s[4][MB][HS];      // 8 KB
  __shared__ float  wih_s[NROW][4];
  __shared__ float  bsum[NROW];
  __shared__ float  xs[MB][4];

  // ---- stage W_ih rows + bias sums ----
  if (tid < NROW) {
    int qq = tid >> 4, jj = tid & 15;
    int grow = qq * Hh + j0 + jj;
    wih_s[tid][0] = Wih[grow * 3 + 0];
    wih_s[tid][1] = Wih[grow * 3 + 1];
    wih_s[tid][2] = Wih[grow * 3 + 2];
    bsum[tid] = bih[grow] + bhh[grow];
  }

  // ---- stage W_hh slice -> LDS bf16 hi/lo, 16B-unit XOR swizzle ----
  for (int idx = tid; idx < NROW * 64; idx += NTHR) {
    int row = idx >> 6, seg = idx & 63;             // row 0..63, seg: 8 floats each
    int qq = row >> 4, jj = row & 15;
    const float* src = Whh + (size_t)(qq * Hh + j0 + jj) * Hh + seg * 8;
    float4 w0 = *(const float4*)(src);
    float4 w1 = *(const float4*)(src + 4);
    float wv[8] = {w0.x, w0.y, w0.z, w0.w, w1.x, w1.y, w1.z, w1.w};
    unsigned uhi[4], ulo[4];
    #pragma unroll
    for (int p = 0; p < 4; ++p) {
      ushort h0 = f2bf(wv[2*p]),   h1 = f2bf(wv[2*p+1]);
      ushort l0 = f2bf(wv[2*p]   - bf2f(h0));
      ushort l1 = f2bf(wv[2*p+1] - bf2f(h1));
      uhi[p] = (unsigned)h0 | ((unsigned)h1 << 16);
      ulo[p] = (unsigned)l0 | ((unsigned)l1 << 16);
    }
    int off = row * 1024 + ((seg * 16) ^ ((row & 7) << 4));
    *(uint4*)((char*)whi + off) = make_uint4(uhi[0], uhi[1], uhi[2], uhi[3]);
    *(uint4*)((char*)wlo + off) = make_uint4(ulo[0], ulo[1], ulo[2], ulo[3]);
  }

  // ---- zero h_0 slice (buffer 0) ----
  {
    int b = tid >> 4, jj = tid & 15;
    size_t o = (size_t)(b0 + b) * Hh + j0 + jj;
    hhi[o] = 0; hlo[o] = 0;
  }
  group_barrier(bar, tid, 32u);

  // ---- per-thread constants ----
  const int l   = tid & 63;
  const int wid = tid >> 6;
  const int m   = wid >> 2;            // 0..1 batch half
  const int q   = wid & 3;             // gate quadrant
  const int lm  = l & 15;
  const int lk  = l >> 4;              // 0..3

  const size_t aoff  = (size_t)(b0 + m * 16 + lm) * Hh + lk * 8;  // ushort idx
  const int    brow  = q * 16 + lm;
  const int    bxor  = (brow & 7) << 4;
  const int    bbyte = brow * 1024;

  const int cb = tid >> 4;             // 0..31 combine batch
  const int cj = tid & 15;             // combine hidden
  float c_state = 0.0f;

  int cur = 0;
  for (int t = 0; t < Tt; ++t) {
    // stage x_t for this batch group
    if (tid < MB * 3) {
      int b = tid / 3, ii = tid - b * 3;
      xs[b][ii] = x[(size_t)(b0 + b) * (Tt * 3) + t * 3 + ii];
    }

    const ushort* Ahi = hhi + (size_t)cur * Bsz * Hh + aoff;
    const ushort* Alo = hlo + (size_t)cur * Bsz * Hh + aoff;
    f32x4 acc0 = {0.f, 0.f, 0.f, 0.f};
    f32x4 acc1 = {0.f, 0.f, 0.f, 0.f};
    #pragma unroll
    for (int kk = 0; kk < 8; ++kk) {
      s16x8 ah0 = *(const s16x8*)(Ahi + kk * 32);
      s16x8 ah1 = *(const s16x8*)(Ahi + (kk + 8) * 32);
      s16x8 al0 = *(const s16x8*)(Alo + kk * 32);
      s16x8 al1 = *(const s16x8*)(Alo + (kk + 8) * 32);
      s16x8 bh0 = *(const s16x8*)((const char*)whi + bbyte + ((kk * 64 + lk * 16) ^ bxor));
      s16x8 bh1 = *(const s16x8*)((const char*)whi + bbyte + (((kk + 8) * 64 + lk * 16) ^ bxor));
      s16x8 bl0 = *(const s16x8*)((const char*)wlo + bbyte + ((kk * 64 + lk * 16) ^ bxor));
      s16x8 bl1 = *(const s16x8*)((const char*)wlo + bbyte + (((kk + 8) * 64 + lk * 16) ^ bxor));
      acc0 = __builtin_amdgcn_mfma_f32_16x16x32_bf16(ah0, bh0, acc0, 0, 0, 0);
      acc1 = __builtin_amdgcn_mfma_f32_16x16x32_bf16(ah1, bh1, acc1, 0, 0, 0);
      acc0 = __builtin_amdgcn_mfma_f32_16x16x32_bf16(ah0, bl0, acc0, 0, 0, 0);
      acc1 = __builtin_amdgcn_mfma_f32_16x16x32_bf16(ah1, bl1, acc1, 0, 0, 0);
      acc0 = __builtin_amdgcn_mfma_f32_16x16x32_bf16(al0, bh0, acc0, 0, 0, 0);
      acc1 = __builtin_amdgcn_mfma_f32_16x16x32_bf16(al1, bh1, acc1, 0, 0, 0);
    }
    f32x4 accs = acc0 + acc1;
    #pragma unroll
    for (int r = 0; r < 4; ++r)
      gates_s[q][m * 16 + lk * 4 + r][lm] = accs[r];
    __syncthreads();

    // ---- gate combine: thread (cb, cj) owns one (batch, hidden) cell ----
    {
      float xv0 = xs[cb][0], xv1 = xs[cb][1], xv2 = xs[cb][2];
      float pre[4];
      #pragma unroll
      for (int qq = 0; qq < 4; ++qq) {
        int r = qq * 16 + cj;
        pre[qq] = gates_s[qq][cb][cj] + bsum[r]
                + xv0 * wih_s[r][0] + xv1 * wih_s[r][1] + xv2 * wih_s[r][2];
      }
      float ig = sigm(pre[0]), fg = sigm(pre[1]);
      float gg = tanhx(pre[2]), og = sigm(pre[3]);
      c_state = fg * c_state + ig * gg;
      float hv = og * tanhx(c_state);
      ushort uh = f2bf(hv);
      ushort ul = f2bf(hv - bf2f(uh));
      size_t ho = (size_t)(cur ^ 1) * Bsz * Hh + (size_t)(b0 + cb) * Hh + j0 + cj;
      hhi[ho] = uh;
      hlo[ho] = ul;
    }

    group_barrier(bar, tid, 32u * (t + 2));
    cur ^= 1;
  }

  // ---- epilogue: wgs hb==0 (wg 0..7) compute FC for their 32 batches ----
  if (hb == 0) {
    const ushort* Hf = hhi + (size_t)cur * Bsz * Hh;
    const ushort* Lf = hlo + (size_t)cur * Bsz * Hh;
    int b = tid >> 4, lj = tid & 15;
    float p = 0.0f;
    for (int jj = lj; jj < Hh; jj += 16) {
      size_t o = (size_t)(b0 + b) * Hh + jj;
      p += (bf2f(Hf[o]) + bf2f(Lf[o])) * fcw[jj];
    }
    ((float*)gates_s)[tid] = p;
    __syncthreads();
    if (lj == 0) {
      float s = 0.0f;
      #pragma unroll
      for (int r = 0; r < 16; ++r) s += ((float*)gates_s)[(b << 4) + r];
      out[b0 + b] = s + fcb[0];
    }
  }
}

extern "C" void kernel_launch(void* const* d_in, const int* in_sizes, int n_in,
                              void* d_out, int out_size, void* d_ws, size_t ws_size,
                              hipStream_t stream) {
  const float* x   = (const float*)d_in[0];
  const float* Wih = (const float*)d_in[1];
  const float* Whh = (const float*)d_in[2];
  const float* bih = (const float*)d_in[3];
  const float* bhh = (const float*)d_in[4];
  const float* fcw = (const float*)d_in[5];
  const float* fcb = (const float*)d_in[6];
  float* out = (float*)d_out;
  char*  ws  = (char*)d_ws;

  hipLaunchKernelGGL(init_ws, dim3(1), dim3(CTRL_UINTS), 0, stream,
                     (unsigned*)(ws + BAR_OFF));
  hipLaunchKernelGGL(lstm_kernel, dim3(NWG), dim3(NTHR), 0, stream,
                     x, Wih, Whh, bih, bhh, fcw, fcb, out, ws);
}

// Round 4
// 8202.321 us; speedup vs baseline: 5.1610x; 5.1610x over previous
//
#include <hip/hip_runtime.h>

// SimpleLSTM B=256, T=512, I=3, H=512. out = fc(h_T).
// Split-bf16 MFMA, W-stationary in LDS. 256 wgs x 512 thr:
//   wg (bb=wg&7, hb=wg>>3): batches bb*32..+31, hidden hb*16..+15 (64 gate rows).
// Cross-wg h exchange via relaxed agent-scope atomics (sc0 sc1: bypass L1/L2,
// served by LLC) -- NO threadfence, so no per-step L2 writeback/invalidate.
// W rows padded to 520 ushorts in LDS (kills the 8-way ds_read_b128 conflict).
// R3 bug fixed: W fragment index is kk*32 USHORTS (was kk*64 = byte-unit leak).

#define Hh   512
#define Bsz  256
#define Tt   512

#define MB   32     // batches per group
#define HS   16     // hidden per wg
#define NROW 64     // gate rows per wg (4 quadrants x 16)
#define NTHR 512
#define NWG  256
#define WPAD 520    // ushorts per W row in LDS (1040 B; 1040 % 128 == 16)

typedef float f32x4 __attribute__((ext_vector_type(4)));
typedef short s16x8 __attribute__((ext_vector_type(8)));
typedef unsigned long long u64;

// ws layout (bytes): hi plane [2][256][512] ushort, lo plane, barrier ctrl
#define PLANE_SZ (2 * Bsz * Hh * 2)          // 512 KB
#define HHI_OFF  0
#define HLO_OFF  (HHI_OFF + PLANE_SZ)
#define BAR_OFF  (HLO_OFF + PLANE_SZ)
#define CTRL_UINTS 256

__device__ __forceinline__ float sigm(float v)  { return 1.0f / (1.0f + __expf(-v)); }
__device__ __forceinline__ float tanhx(float v) { return 2.0f / (1.0f + __expf(-2.0f * v)) - 1.0f; }

__device__ __forceinline__ ushort f2bf(float f) {   // RNE
  unsigned u = __float_as_uint(f);
  return (ushort)((u + 0x7FFFu + ((u >> 16) & 1u)) >> 16);
}
__device__ __forceinline__ float bf2f(ushort u) {
  return __uint_as_float((unsigned)u << 16);
}

// 16B fragment load from LLC-coherent plane (two relaxed agent-scope b64 loads
// -> global_load_dwordx2 sc0 sc1; compiler tracks vmcnt, no fences emitted).
__device__ __forceinline__ s16x8 ld_frag(const ushort* p) {
  const u64* q = (const u64*)p;
  union { u64 w[2]; s16x8 v; } u;
  u.w[0] = __hip_atomic_load(q,     __ATOMIC_RELAXED, __HIP_MEMORY_SCOPE_AGENT);
  u.w[1] = __hip_atomic_load(q + 1, __ATOMIC_RELAXED, __HIP_MEMORY_SCOPE_AGENT);
  return u.v;
}

// Group barrier. Explicit vmcnt(0) guarantees our sc0sc1 h-stores reached the
// coherence point before the counter increment (don't rely on __syncthreads'
// implicit drain). Counter is a relaxed agent-scope atomic at LLC.
__device__ __forceinline__ void group_barrier(unsigned* bar, int tid, unsigned target) {
  asm volatile("s_waitcnt vmcnt(0)" ::: "memory");
  __syncthreads();
  if (tid == 0) {
    __hip_atomic_fetch_add(bar, 1u, __ATOMIC_RELAXED, __HIP_MEMORY_SCOPE_AGENT);
    while (__hip_atomic_load(bar, __ATOMIC_RELAXED, __HIP_MEMORY_SCOPE_AGENT) < target)
      __builtin_amdgcn_s_sleep(2);
  }
  __syncthreads();
}

__global__ void init_ws(unsigned* ctrl) {
  ctrl[threadIdx.x] = 0u;
}

__global__ __launch_bounds__(NTHR, 1)
void lstm_kernel(const float* __restrict__ x,   const float* __restrict__ Wih,
                 const float* __restrict__ Whh, const float* __restrict__ bih,
                 const float* __restrict__ bhh, const float* __restrict__ fcw,
                 const float* __restrict__ fcb, float* __restrict__ out,
                 char* __restrict__ ws)
{
  const int tid = threadIdx.x;
  const int wg  = blockIdx.x;
  const int bb  = wg & 7;
  const int hb  = wg >> 3;
  const int j0  = hb * HS;
  const int b0  = bb * MB;

  ushort*   hhi = (ushort*)(ws + HHI_OFF);
  ushort*   hlo = (ushort*)(ws + HLO_OFF);
  unsigned* bar = (unsigned*)(ws + BAR_OFF) + bb * 16;

  __shared__ ushort whi[NROW * WPAD];        // 65 KB, row-padded
  __shared__ ushort wlo[NROW * WPAD];        // 65 KB
  __shared__ float  gates_s[4][MB][17];      // 8.5 KB, padded
  __shared__ float  wih_s[NROW][3];
  __shared__ float  bsum[NROW];
  __shared__ float  xs[MB][3];
  __shared__ ushort hstg[MB][16];            // h hi staging for packed store
  __shared__ ushort lstg[MB][16];

  // ---- stage W_ih rows + bias sums ----
  if (tid < NROW) {
    int qq = tid >> 4, jj = tid & 15;
    int grow = qq * Hh + j0 + jj;
    wih_s[tid][0] = Wih[grow * 3 + 0];
    wih_s[tid][1] = Wih[grow * 3 + 1];
    wih_s[tid][2] = Wih[grow * 3 + 2];
    bsum[tid] = bih[grow] + bhh[grow];
  }

  // ---- stage W_hh slice -> LDS bf16 hi/lo, padded rows ----
  for (int idx = tid; idx < NROW * 64; idx += NTHR) {
    int row = idx >> 6, seg = idx & 63;             // seg: 8 floats
    int qq = row >> 4, jj = row & 15;
    const float* src = Whh + (size_t)(qq * Hh + j0 + jj) * Hh + seg * 8;
    float4 w0 = *(const float4*)(src);
    float4 w1 = *(const float4*)(src + 4);
    float wv[8] = {w0.x, w0.y, w0.z, w0.w, w1.x, w1.y, w1.z, w1.w};
    unsigned uhi[4], ulo[4];
    #pragma unroll
    for (int p = 0; p < 4; ++p) {
      ushort h0 = f2bf(wv[2*p]),   h1 = f2bf(wv[2*p+1]);
      ushort l0 = f2bf(wv[2*p]   - bf2f(h0));
      ushort l1 = f2bf(wv[2*p+1] - bf2f(h1));
      uhi[p] = (unsigned)h0 | ((unsigned)h1 << 16);
      ulo[p] = (unsigned)l0 | ((unsigned)l1 << 16);
    }
    *(uint4*)&whi[row * WPAD + seg * 8] = make_uint4(uhi[0], uhi[1], uhi[2], uhi[3]);
    *(uint4*)&wlo[row * WPAD + seg * 8] = make_uint4(ulo[0], ulo[1], ulo[2], ulo[3]);
  }

  // ---- zero h_0 slice (buffer 0) via coherent stores ----
  {
    int b = tid >> 4, jj = tid & 15;
    size_t o = (size_t)(b0 + b) * Hh + j0 + jj;
    __hip_atomic_store(&hhi[o], (ushort)0, __ATOMIC_RELAXED, __HIP_MEMORY_SCOPE_AGENT);
    __hip_atomic_store(&hlo[o], (ushort)0, __ATOMIC_RELAXED, __HIP_MEMORY_SCOPE_AGENT);
  }
  group_barrier(bar, tid, 32u);

  // ---- per-thread constants ----
  const int l   = tid & 63;
  const int wid = tid >> 6;
  const int m   = wid >> 2;            // batch half
  const int q   = wid & 3;             // gate quadrant
  const int lm  = l & 15;
  const int lk  = l >> 4;

  const size_t aoff = (size_t)(b0 + m * 16 + lm) * Hh + lk * 8;  // ushort idx
  const int    brow = (q * 16 + lm) * WPAD + lk * 8;             // LDS ushort idx

  const int cb = tid >> 4;             // combine batch
  const int cj = tid & 15;             // combine hidden
  float c_state = 0.0f;

  int cur = 0;
  for (int t = 0; t < Tt; ++t) {
    if (tid < MB * 3) {
      int b = tid / 3, ii = tid - b * 3;
      xs[b][ii] = x[(size_t)(b0 + b) * (Tt * 3) + t * 3 + ii];
    }

    const ushort* Ahi = hhi + (size_t)cur * Bsz * Hh + aoff;
    const ushort* Alo = hlo + (size_t)cur * Bsz * Hh + aoff;
    f32x4 acc0 = {0.f, 0.f, 0.f, 0.f};
    f32x4 acc1 = {0.f, 0.f, 0.f, 0.f};
    #pragma unroll
    for (int kk = 0; kk < 8; ++kk) {
      s16x8 ah0 = ld_frag(Ahi + kk * 32);
      s16x8 ah1 = ld_frag(Ahi + (kk + 8) * 32);
      s16x8 al0 = ld_frag(Alo + kk * 32);
      s16x8 al1 = ld_frag(Alo + (kk + 8) * 32);
      s16x8 bh0 = *(const s16x8*)&whi[brow + kk * 32];
      s16x8 bh1 = *(const s16x8*)&whi[brow + (kk + 8) * 32];
      s16x8 bl0 = *(const s16x8*)&wlo[brow + kk * 32];
      s16x8 bl1 = *(const s16x8*)&wlo[brow + (kk + 8) * 32];
      acc0 = __builtin_amdgcn_mfma_f32_16x16x32_bf16(ah0, bh0, acc0, 0, 0, 0);
      acc1 = __builtin_amdgcn_mfma_f32_16x16x32_bf16(ah1, bh1, acc1, 0, 0, 0);
      acc0 = __builtin_amdgcn_mfma_f32_16x16x32_bf16(ah0, bl0, acc0, 0, 0, 0);
      acc1 = __builtin_amdgcn_mfma_f32_16x16x32_bf16(ah1, bl1, acc1, 0, 0, 0);
      acc0 = __builtin_amdgcn_mfma_f32_16x16x32_bf16(al0, bh0, acc0, 0, 0, 0);
      acc1 = __builtin_amdgcn_mfma_f32_16x16x32_bf16(al1, bh1, acc1, 0, 0, 0);
    }
    f32x4 accs = acc0 + acc1;
    #pragma unroll
    for (int r = 0; r < 4; ++r)
      gates_s[q][m * 16 + lk * 4 + r][lm] = accs[r];
    __syncthreads();

    // ---- gate combine: thread (cb, cj) owns one (batch, hidden) cell ----
    {
      float xv0 = xs[cb][0], xv1 = xs[cb][1], xv2 = xs[cb][2];
      float pre[4];
      #pragma unroll
      for (int qq = 0; qq < 4; ++qq) {
        int r = qq * 16 + cj;
        pre[qq] = gates_s[qq][cb][cj] + bsum[r]
                + xv0 * wih_s[r][0] + xv1 * wih_s[r][1] + xv2 * wih_s[r][2];
      }
      float ig = sigm(pre[0]), fg = sigm(pre[1]);
      float gg = tanhx(pre[2]), og = sigm(pre[3]);
      c_state = fg * c_state + ig * gg;
      float hv = og * tanhx(c_state);
      ushort uh = f2bf(hv);
      hstg[cb][cj] = uh;
      lstg[cb][cj] = f2bf(hv - bf2f(uh));
    }
    __syncthreads();

    // ---- packed coherent store of h slice (uint = 2 bf16, memory order) ----
    if (tid < 256) {
      int b = tid >> 3, jp = tid & 7;
      unsigned wh = (unsigned)hstg[b][2 * jp] | ((unsigned)hstg[b][2 * jp + 1] << 16);
      unsigned wl = (unsigned)lstg[b][2 * jp] | ((unsigned)lstg[b][2 * jp + 1] << 16);
      size_t wordo = ((size_t)(cur ^ 1) * Bsz * Hh + (size_t)(b0 + b) * Hh + j0) / 2 + jp;
      __hip_atomic_store((unsigned*)hhi + wordo, wh, __ATOMIC_RELAXED, __HIP_MEMORY_SCOPE_AGENT);
      __hip_atomic_store((unsigned*)hlo + wordo, wl, __ATOMIC_RELAXED, __HIP_MEMORY_SCOPE_AGENT);
    }

    group_barrier(bar, tid, 32u * (t + 2));
    cur ^= 1;
  }

  // ---- epilogue: wgs hb==0 compute FC for their 32 batches ----
  if (hb == 0) {
    const unsigned* Hf = (const unsigned*)(hhi + (size_t)cur * Bsz * Hh);
    const unsigned* Lf = (const unsigned*)(hlo + (size_t)cur * Bsz * Hh);
    int b = tid >> 4, lj = tid & 15;
    float p = 0.0f;
    for (int jp = lj; jp < Hh / 2; jp += 16) {
      size_t o = (size_t)(b0 + b) * (Hh / 2) + jp;
      unsigned uh = __hip_atomic_load(Hf + o, __ATOMIC_RELAXED, __HIP_MEMORY_SCOPE_AGENT);
      unsigned ul = __hip_atomic_load(Lf + o, __ATOMIC_RELAXED, __HIP_MEMORY_SCOPE_AGENT);
      float h0 = bf2f((ushort)(uh & 0xFFFF)) + bf2f((ushort)(ul & 0xFFFF));
      float h1 = bf2f((ushort)(uh >> 16))    + bf2f((ushort)(ul >> 16));
      p += h0 * fcw[2 * jp] + h1 * fcw[2 * jp + 1];
    }
    ((float*)gates_s)[tid] = p;
    __syncthreads();
    if (lj == 0) {
      float s = 0.0f;
      #pragma unroll
      for (int r = 0; r < 16; ++r) s += ((float*)gates_s)[(b << 4) + r];
      out[b0 + b] = s + fcb[0];
    }
  }
}

extern "C" void kernel_launch(void* const* d_in, const int* in_sizes, int n_in,
                              void* d_out, int out_size, void* d_ws, size_t ws_size,
                              hipStream_t stream) {
  const float* x   = (const float*)d_in[0];
  const float* Wih = (const float*)d_in[1];
  const float* Whh = (const float*)d_in[2];
  const float* bih = (const float*)d_in[3];
  const float* bhh = (const float*)d_in[4];
  const float* fcw = (const float*)d_in[5];
  const float* fcb = (const float*)d_in[6];
  float* out = (float*)d_out;
  char*  ws  = (char*)d_ws;

  hipLaunchKernelGGL(init_ws, dim3(1), dim3(CTRL_UINTS), 0, stream,
                     (unsigned*)(ws + BAR_OFF));
  hipLaunchKernelGGL(lstm_kernel, dim3(NWG), dim3(NTHR), 0, stream,
                     x, Wih, Whh, bih, bhh, fcw, fcb, out, ws);
}

// Round 7
// 4934.498 us; speedup vs baseline: 8.5789x; 1.6622x over previous
//
#include <hip/hip_runtime.h>

// SimpleLSTM B=256, T=512, I=3, H=512. out = fc(h_T).
// DIAGNOSTIC ROUND: exact R4 structure (known-pass, 8.2ms), ONE change only:
// A-fragment loads switched from 64 serialized __hip_atomic_load u64 to
// 32 batched inline-asm global_load_dwordx4 sc0 sc1 + single vmcnt(0) wait
// (rule #18: waitcnt + sched_barrier(0) before MFMA consumption).
// Everything else identical to R4 (WPAD W LDS, 2m x 4q waves, atomic stores,
// per-group LLC atomic barrier).

#define Hh   512
#define Bsz  256
#define Tt   512

#define MB   32
#define HS   16
#define NROW 64
#define NTHR 512
#define NWG  256
#define WPAD 520

typedef float f32x4 __attribute__((ext_vector_type(4)));
typedef short s16x8 __attribute__((ext_vector_type(8)));
typedef unsigned long long u64;

#define PLANE_SZ (2 * Bsz * Hh * 2)          // 512 KB
#define HHI_OFF  0
#define HLO_OFF  (HHI_OFF + PLANE_SZ)
#define BAR_OFF  (HLO_OFF + PLANE_SZ)
#define CTRL_UINTS 256

__device__ __forceinline__ float sigm(float v)  { return 1.0f / (1.0f + __expf(-v)); }
__device__ __forceinline__ float tanhx(float v) { return 2.0f / (1.0f + __expf(-2.0f * v)) - 1.0f; }

__device__ __forceinline__ ushort f2bf(float f) {   // RNE
  unsigned u = __float_as_uint(f);
  return (ushort)((u + 0x7FFFu + ((u >> 16) & 1u)) >> 16);
}
__device__ __forceinline__ float bf2f(ushort u) {
  return __uint_as_float((unsigned)u << 16);
}

#define GLOAD(dst, base, imm)                                            \
  asm volatile("global_load_dwordx4 %0, %1, off offset:%c2 sc0 sc1"      \
               : "=v"(dst) : "v"(base), "i"(imm))

__device__ __forceinline__ void group_barrier(unsigned* bar, int tid, unsigned target) {
  asm volatile("s_waitcnt vmcnt(0)" ::: "memory");
  __syncthreads();
  if (tid == 0) {
    __hip_atomic_fetch_add(bar, 1u, __ATOMIC_RELAXED, __HIP_MEMORY_SCOPE_AGENT);
    while (__hip_atomic_load(bar, __ATOMIC_RELAXED, __HIP_MEMORY_SCOPE_AGENT) < target)
      __builtin_amdgcn_s_sleep(2);
  }
  __syncthreads();
}

__global__ void init_ws(unsigned* ctrl) {
  ctrl[threadIdx.x] = 0u;
}

__global__ __launch_bounds__(NTHR, 2)
void lstm_kernel(const float* __restrict__ x,   const float* __restrict__ Wih,
                 const float* __restrict__ Whh, const float* __restrict__ bih,
                 const float* __restrict__ bhh, const float* __restrict__ fcw,
                 const float* __restrict__ fcb, float* __restrict__ out,
                 char* __restrict__ ws)
{
  const int tid = threadIdx.x;
  const int wg  = blockIdx.x;
  const int bb  = wg & 7;
  const int hb  = wg >> 3;
  const int j0  = hb * HS;
  const int b0  = bb * MB;

  ushort*   hhi = (ushort*)(ws + HHI_OFF);
  ushort*   hlo = (ushort*)(ws + HLO_OFF);
  unsigned* bar = (unsigned*)(ws + BAR_OFF) + bb * 16;

  __shared__ ushort whi[NROW * WPAD];
  __shared__ ushort wlo[NROW * WPAD];
  __shared__ float  gates_s[4][MB][17];
  __shared__ float  wih_s[NROW][3];
  __shared__ float  bsum[NROW];
  __shared__ float  xs[MB][3];
  __shared__ ushort hstg[MB][16];
  __shared__ ushort lstg[MB][16];

  if (tid < NROW) {
    int qq = tid >> 4, jj = tid & 15;
    int grow = qq * Hh + j0 + jj;
    wih_s[tid][0] = Wih[grow * 3 + 0];
    wih_s[tid][1] = Wih[grow * 3 + 1];
    wih_s[tid][2] = Wih[grow * 3 + 2];
    bsum[tid] = bih[grow] + bhh[grow];
  }

  for (int idx = tid; idx < NROW * 64; idx += NTHR) {
    int row = idx >> 6, seg = idx & 63;
    int qq = row >> 4, jj = row & 15;
    const float* src = Whh + (size_t)(qq * Hh + j0 + jj) * Hh + seg * 8;
    float4 w0 = *(const float4*)(src);
    float4 w1 = *(const float4*)(src + 4);
    float wv[8] = {w0.x, w0.y, w0.z, w0.w, w1.x, w1.y, w1.z, w1.w};
    unsigned uhi[4], ulo[4];
    #pragma unroll
    for (int p = 0; p < 4; ++p) {
      ushort h0 = f2bf(wv[2*p]),   h1 = f2bf(wv[2*p+1]);
      ushort l0 = f2bf(wv[2*p]   - bf2f(h0));
      ushort l1 = f2bf(wv[2*p+1] - bf2f(h1));
      uhi[p] = (unsigned)h0 | ((unsigned)h1 << 16);
      ulo[p] = (unsigned)l0 | ((unsigned)l1 << 16);
    }
    *(uint4*)&whi[row * WPAD + seg * 8] = make_uint4(uhi[0], uhi[1], uhi[2], uhi[3]);
    *(uint4*)&wlo[row * WPAD + seg * 8] = make_uint4(ulo[0], ulo[1], ulo[2], ulo[3]);
  }

  {
    int b = tid >> 4, jj = tid & 15;
    size_t o = (size_t)(b0 + b) * Hh + j0 + jj;
    __hip_atomic_store(&hhi[o], (ushort)0, __ATOMIC_RELAXED, __HIP_MEMORY_SCOPE_AGENT);
    __hip_atomic_store(&hlo[o], (ushort)0, __ATOMIC_RELAXED, __HIP_MEMORY_SCOPE_AGENT);
  }
  group_barrier(bar, tid, 32u);

  const int l   = tid & 63;
  const int wid = tid >> 6;
  const int m   = wid >> 2;            // batch half
  const int q   = wid & 3;             // gate quadrant
  const int lm  = l & 15;
  const int lk  = l >> 4;

  const size_t aoff = (size_t)(b0 + m * 16 + lm) * Hh + lk * 8;  // ushort idx
  const int    brow = (q * 16 + lm) * WPAD + lk * 8;             // LDS ushort idx

  const int cb = tid >> 4;
  const int cj = tid & 15;
  float c_state = 0.0f;

  int cur = 0;
  for (int t = 0; t < Tt; ++t) {
    if (tid < MB * 3) {
      int b = tid / 3, ii = tid - b * 3;
      xs[b][ii] = x[(size_t)(b0 + b) * (Tt * 3) + t * 3 + ii];
    }

    // ---- issue all 32 A-fragment loads (pipelined), single drain ----
    const char* pH = (const char*)(hhi + (size_t)cur * Bsz * Hh + aoff);
    const char* pL = (const char*)(hlo + (size_t)cur * Bsz * Hh + aoff);
    f32x4 AHa[8], AHb[8], ALa[8], ALb[8];   // a: k-blocks 0..7, b: 8..15
    GLOAD(AHa[0], pH, 0);   GLOAD(AHa[1], pH, 64);  GLOAD(AHa[2], pH, 128); GLOAD(AHa[3], pH, 192);
    GLOAD(AHa[4], pH, 256); GLOAD(AHa[5], pH, 320); GLOAD(AHa[6], pH, 384); GLOAD(AHa[7], pH, 448);
    GLOAD(AHb[0], pH, 512); GLOAD(AHb[1], pH, 576); GLOAD(AHb[2], pH, 640); GLOAD(AHb[3], pH, 704);
    GLOAD(AHb[4], pH, 768); GLOAD(AHb[5], pH, 832); GLOAD(AHb[6], pH, 896); GLOAD(AHb[7], pH, 960);
    GLOAD(ALa[0], pL, 0);   GLOAD(ALa[1], pL, 64);  GLOAD(ALa[2], pL, 128); GLOAD(ALa[3], pL, 192);
    GLOAD(ALa[4], pL, 256); GLOAD(ALa[5], pL, 320); GLOAD(ALa[6], pL, 384); GLOAD(ALa[7], pL, 448);
    GLOAD(ALb[0], pL, 512); GLOAD(ALb[1], pL, 576); GLOAD(ALb[2], pL, 640); GLOAD(ALb[3], pL, 704);
    GLOAD(ALb[4], pL, 768); GLOAD(ALb[5], pL, 832); GLOAD(ALb[6], pL, 896); GLOAD(ALb[7], pL, 960);
    asm volatile("s_waitcnt vmcnt(0)" ::: "memory");
    __builtin_amdgcn_sched_barrier(0);

    f32x4 acc0 = {0.f, 0.f, 0.f, 0.f};
    f32x4 acc1 = {0.f, 0.f, 0.f, 0.f};
    #pragma unroll
    for (int kk = 0; kk < 8; ++kk) {
      s16x8 ah0 = __builtin_bit_cast(s16x8, AHa[kk]);
      s16x8 ah1 = __builtin_bit_cast(s16x8, AHb[kk]);
      s16x8 al0 = __builtin_bit_cast(s16x8, ALa[kk]);
      s16x8 al1 = __builtin_bit_cast(s16x8, ALb[kk]);
      s16x8 bh0 = *(const s16x8*)&whi[brow + kk * 32];
      s16x8 bh1 = *(const s16x8*)&whi[brow + (kk + 8) * 32];
      s16x8 bl0 = *(const s16x8*)&wlo[brow + kk * 32];
      s16x8 bl1 = *(const s16x8*)&wlo[brow + (kk + 8) * 32];
      acc0 = __builtin_amdgcn_mfma_f32_16x16x32_bf16(ah0, bh0, acc0, 0, 0, 0);
      acc1 = __builtin_amdgcn_mfma_f32_16x16x32_bf16(ah1, bh1, acc1, 0, 0, 0);
      acc0 = __builtin_amdgcn_mfma_f32_16x16x32_bf16(ah0, bl0, acc0, 0, 0, 0);
      acc1 = __builtin_amdgcn_mfma_f32_16x16x32_bf16(ah1, bl1, acc1, 0, 0, 0);
      acc0 = __builtin_amdgcn_mfma_f32_16x16x32_bf16(al0, bh0, acc0, 0, 0, 0);
      acc1 = __builtin_amdgcn_mfma_f32_16x16x32_bf16(al1, bh1, acc1, 0, 0, 0);
    }
    f32x4 accs = acc0 + acc1;
    #pragma unroll
    for (int r = 0; r < 4; ++r)
      gates_s[q][m * 16 + lk * 4 + r][lm] = accs[r];
    __syncthreads();

    {
      float xv0 = xs[cb][0], xv1 = xs[cb][1], xv2 = xs[cb][2];
      float pre[4];
      #pragma unroll
      for (int qq = 0; qq < 4; ++qq) {
        int r = qq * 16 + cj;
        pre[qq] = gates_s[qq][cb][cj] + bsum[r]
                + xv0 * wih_s[r][0] + xv1 * wih_s[r][1] + xv2 * wih_s[r][2];
      }
      float ig = sigm(pre[0]), fg = sigm(pre[1]);
      float gg = tanhx(pre[2]), og = sigm(pre[3]);
      c_state = fg * c_state + ig * gg;
      float hv = og * tanhx(c_state);
      ushort uh = f2bf(hv);
      hstg[cb][cj] = uh;
      lstg[cb][cj] = f2bf(hv - bf2f(uh));
    }
    __syncthreads();

    if (tid < 256) {
      int b = tid >> 3, jp = tid & 7;
      unsigned wh = (unsigned)hstg[b][2 * jp] | ((unsigned)hstg[b][2 * jp + 1] << 16);
      unsigned wl = (unsigned)lstg[b][2 * jp] | ((unsigned)lstg[b][2 * jp + 1] << 16);
      size_t wordo = ((size_t)(cur ^ 1) * Bsz * Hh + (size_t)(b0 + b) * Hh + j0) / 2 + jp;
      __hip_atomic_store((unsigned*)hhi + wordo, wh, __ATOMIC_RELAXED, __HIP_MEMORY_SCOPE_AGENT);
      __hip_atomic_store((unsigned*)hlo + wordo, wl, __ATOMIC_RELAXED, __HIP_MEMORY_SCOPE_AGENT);
    }

    group_barrier(bar, tid, 32u * (t + 2));
    cur ^= 1;
  }

  if (hb == 0) {
    const u64* Hf = (const u64*)(hhi + (size_t)cur * Bsz * Hh);
    const u64* Lf = (const u64*)(hlo + (size_t)cur * Bsz * Hh);
    int b = tid >> 4, lj = tid & 15;
    float p = 0.0f;
    for (int jq = lj; jq < Hh / 4; jq += 16) {
      size_t o = (size_t)(b0 + b) * (Hh / 4) + jq;
      u64 uh = __hip_atomic_load(Hf + o, __ATOMIC_RELAXED, __HIP_MEMORY_SCOPE_AGENT);
      u64 ul = __hip_atomic_load(Lf + o, __ATOMIC_RELAXED, __HIP_MEMORY_SCOPE_AGENT);
      #pragma unroll
      for (int e = 0; e < 4; ++e) {
        float hv = bf2f((ushort)(uh >> (16 * e))) + bf2f((ushort)(ul >> (16 * e)));
        p += hv * fcw[4 * jq + e];
      }
    }
    ((float*)gates_s)[tid] = p;
    __syncthreads();
    if (lj == 0) {
      float s = 0.0f;
      #pragma unroll
      for (int r = 0; r < 16; ++r) s += ((float*)gates_s)[(b << 4) + r];
      out[b0 + b] = s + fcb[0];
    }
  }
}

extern "C" void kernel_launch(void* const* d_in, const int* in_sizes, int n_in,
                              void* d_out, int out_size, void* d_ws, size_t ws_size,
                              hipStream_t stream) {
  const float* x   = (const float*)d_in[0];
  const float* Wih = (const float*)d_in[1];
  const float* Whh = (const float*)d_in[2];
  const float* bih = (const float*)d_in[3];
  const float* bhh = (const float*)d_in[4];
  const float* fcw = (const float*)d_in[5];
  const float* fcb = (const float*)d_in[6];
  float* out = (float*)d_out;
  char*  ws  = (char*)d_ws;

  hipLaunchKernelGGL(init_ws, dim3(1), dim3(CTRL_UINTS), 0, stream,
                     (unsigned*)(ws + BAR_OFF));
  hipLaunchKernelGGL(lstm_kernel, dim3(NWG), dim3(NTHR), 0, stream,
                     x, Wih, Whh, bih, bhh, fcw, fcb, out, ws);
}

// Round 8
// 2499.690 us; speedup vs baseline: 16.9350x; 1.9740x over previous
//
#include <hip/hip_runtime.h>

// SimpleLSTM B=256, T=512, I=3, H=512. out = fc(h_T).
// R8: one structural change vs R7 (known-pass, 4.93ms): waves re-split from
// (m, quadrant) to (m, ks=K-quarter). Each wave loads a DISTINCT A K-quarter
// (hi+lo) and computes all 4 gate quadrants over it -> A coherent-read traffic
// cut 4x (256KB -> 64KB per wg per step). K-partials reduced via two-stage
// LDS buffer gates2[2][4][32][17]. All else identical to R7: WPAD W LDS,
// batched GLOAD sc0sc1 + single vmcnt drain, atomic h-stores, LLC barrier.

#define Hh   512
#define Bsz  256
#define Tt   512

#define MB   32
#define HS   16
#define NROW 64
#define NTHR 512
#define NWG  256
#define WPAD 520

typedef float f32x4 __attribute__((ext_vector_type(4)));
typedef short s16x8 __attribute__((ext_vector_type(8)));
typedef unsigned long long u64;

#define PLANE_SZ (2 * Bsz * Hh * 2)          // 512 KB
#define HHI_OFF  0
#define HLO_OFF  (HHI_OFF + PLANE_SZ)
#define BAR_OFF  (HLO_OFF + PLANE_SZ)
#define CTRL_UINTS 256

__device__ __forceinline__ float sigm(float v)  { return 1.0f / (1.0f + __expf(-v)); }
__device__ __forceinline__ float tanhx(float v) { return 2.0f / (1.0f + __expf(-2.0f * v)) - 1.0f; }

__device__ __forceinline__ ushort f2bf(float f) {   // RNE
  unsigned u = __float_as_uint(f);
  return (ushort)((u + 0x7FFFu + ((u >> 16) & 1u)) >> 16);
}
__device__ __forceinline__ float bf2f(ushort u) {
  return __uint_as_float((unsigned)u << 16);
}

#define GLOAD(dst, base, imm)                                            \
  asm volatile("global_load_dwordx4 %0, %1, off offset:%c2 sc0 sc1"      \
               : "=v"(dst) : "v"(base), "i"(imm))

__device__ __forceinline__ void group_barrier(unsigned* bar, int tid, unsigned target) {
  asm volatile("s_waitcnt vmcnt(0)" ::: "memory");
  __syncthreads();
  if (tid == 0) {
    __hip_atomic_fetch_add(bar, 1u, __ATOMIC_RELAXED, __HIP_MEMORY_SCOPE_AGENT);
    while (__hip_atomic_load(bar, __ATOMIC_RELAXED, __HIP_MEMORY_SCOPE_AGENT) < target)
      __builtin_amdgcn_s_sleep(2);
  }
  __syncthreads();
}

__global__ void init_ws(unsigned* ctrl) {
  ctrl[threadIdx.x] = 0u;
}

__global__ __launch_bounds__(NTHR, 2)
void lstm_kernel(const float* __restrict__ x,   const float* __restrict__ Wih,
                 const float* __restrict__ Whh, const float* __restrict__ bih,
                 const float* __restrict__ bhh, const float* __restrict__ fcw,
                 const float* __restrict__ fcb, float* __restrict__ out,
                 char* __restrict__ ws)
{
  const int tid = threadIdx.x;
  const int wg  = blockIdx.x;
  const int bb  = wg & 7;
  const int hb  = wg >> 3;
  const int j0  = hb * HS;
  const int b0  = bb * MB;

  ushort*   hhi = (ushort*)(ws + HHI_OFF);
  ushort*   hlo = (ushort*)(ws + HLO_OFF);
  unsigned* bar = (unsigned*)(ws + BAR_OFF) + bb * 16;

  __shared__ ushort whi[NROW * WPAD];
  __shared__ ushort wlo[NROW * WPAD];
  __shared__ float  gates2[2][4][MB][17];    // two-stage K-partials
  __shared__ float  wih_s[NROW][3];
  __shared__ float  bsum[NROW];
  __shared__ float  xs[MB][3];
  __shared__ ushort hstg[MB][16];
  __shared__ ushort lstg[MB][16];

  if (tid < NROW) {
    int qq = tid >> 4, jj = tid & 15;
    int grow = qq * Hh + j0 + jj;
    wih_s[tid][0] = Wih[grow * 3 + 0];
    wih_s[tid][1] = Wih[grow * 3 + 1];
    wih_s[tid][2] = Wih[grow * 3 + 2];
    bsum[tid] = bih[grow] + bhh[grow];
  }

  for (int idx = tid; idx < NROW * 64; idx += NTHR) {
    int row = idx >> 6, seg = idx & 63;
    int qq = row >> 4, jj = row & 15;
    const float* src = Whh + (size_t)(qq * Hh + j0 + jj) * Hh + seg * 8;
    float4 w0 = *(const float4*)(src);
    float4 w1 = *(const float4*)(src + 4);
    float wv[8] = {w0.x, w0.y, w0.z, w0.w, w1.x, w1.y, w1.z, w1.w};
    unsigned uhi[4], ulo[4];
    #pragma unroll
    for (int p = 0; p < 4; ++p) {
      ushort h0 = f2bf(wv[2*p]),   h1 = f2bf(wv[2*p+1]);
      ushort l0 = f2bf(wv[2*p]   - bf2f(h0));
      ushort l1 = f2bf(wv[2*p+1] - bf2f(h1));
      uhi[p] = (unsigned)h0 | ((unsigned)h1 << 16);
      ulo[p] = (unsigned)l0 | ((unsigned)l1 << 16);
    }
    *(uint4*)&whi[row * WPAD + seg * 8] = make_uint4(uhi[0], uhi[1], uhi[2], uhi[3]);
    *(uint4*)&wlo[row * WPAD + seg * 8] = make_uint4(ulo[0], ulo[1], ulo[2], ulo[3]);
  }

  {
    int b = tid >> 4, jj = tid & 15;
    size_t o = (size_t)(b0 + b) * Hh + j0 + jj;
    __hip_atomic_store(&hhi[o], (ushort)0, __ATOMIC_RELAXED, __HIP_MEMORY_SCOPE_AGENT);
    __hip_atomic_store(&hlo[o], (ushort)0, __ATOMIC_RELAXED, __HIP_MEMORY_SCOPE_AGENT);
  }
  group_barrier(bar, tid, 32u);

  const int l   = tid & 63;
  const int wid = tid >> 6;
  const int m   = wid >> 2;            // batch half (0..1)
  const int ks  = wid & 3;             // K quarter (0..3), 128 elems each
  const int lm  = l & 15;
  const int lk  = l >> 4;              // 0..3

  // A: batch row (b0 + m*16 + lm), k = ks*128 + lk*8 (+u*32 per GLOAD)
  const size_t aoff  = (size_t)(b0 + m * 16 + lm) * Hh + ks * 128 + lk * 8;
  // B (LDS): quadrant q row (q*16+lm), k-block (ks*4+u), lane sub-col lk*8
  const int    brow0 = lm * WPAD + ks * 128 + lk * 8;

  const int cb = tid >> 4;
  const int cj = tid & 15;
  float c_state = 0.0f;

  int cur = 0;
  for (int t = 0; t < Tt; ++t) {
    if (tid < MB * 3) {
      int b = tid / 3, ii = tid - b * 3;
      xs[b][ii] = x[(size_t)(b0 + b) * (Tt * 3) + t * 3 + ii];
    }

    // ---- 8 pipelined A loads (this wave's distinct K-quarter, hi+lo) ----
    const char* pH = (const char*)(hhi + (size_t)cur * Bsz * Hh + aoff);
    const char* pL = (const char*)(hlo + (size_t)cur * Bsz * Hh + aoff);
    f32x4 AH[4], AL[4];
    GLOAD(AH[0], pH, 0);  GLOAD(AH[1], pH, 64);  GLOAD(AH[2], pH, 128); GLOAD(AH[3], pH, 192);
    GLOAD(AL[0], pL, 0);  GLOAD(AL[1], pL, 64);  GLOAD(AL[2], pL, 128); GLOAD(AL[3], pL, 192);
    asm volatile("s_waitcnt vmcnt(0)" ::: "memory");
    __builtin_amdgcn_sched_barrier(0);

    // ---- 4 quadrants x 4 k-blocks x 3 split terms = 48 MFMAs ----
    f32x4 acc0 = {0.f,0.f,0.f,0.f}, acc1 = {0.f,0.f,0.f,0.f};
    f32x4 acc2 = {0.f,0.f,0.f,0.f}, acc3 = {0.f,0.f,0.f,0.f};
    #pragma unroll
    for (int u = 0; u < 4; ++u) {
      s16x8 ah = __builtin_bit_cast(s16x8, AH[u]);
      s16x8 al = __builtin_bit_cast(s16x8, AL[u]);
      {
        s16x8 bh = *(const s16x8*)&whi[0 * 16 * WPAD + brow0 + u * 32];
        s16x8 bl = *(const s16x8*)&wlo[0 * 16 * WPAD + brow0 + u * 32];
        acc0 = __builtin_amdgcn_mfma_f32_16x16x32_bf16(ah, bh, acc0, 0, 0, 0);
        acc0 = __builtin_amdgcn_mfma_f32_16x16x32_bf16(ah, bl, acc0, 0, 0, 0);
        acc0 = __builtin_amdgcn_mfma_f32_16x16x32_bf16(al, bh, acc0, 0, 0, 0);
      }
      {
        s16x8 bh = *(const s16x8*)&whi[1 * 16 * WPAD + brow0 + u * 32];
        s16x8 bl = *(const s16x8*)&wlo[1 * 16 * WPAD + brow0 + u * 32];
        acc1 = __builtin_amdgcn_mfma_f32_16x16x32_bf16(ah, bh, acc1, 0, 0, 0);
        acc1 = __builtin_amdgcn_mfma_f32_16x16x32_bf16(ah, bl, acc1, 0, 0, 0);
        acc1 = __builtin_amdgcn_mfma_f32_16x16x32_bf16(al, bh, acc1, 0, 0, 0);
      }
      {
        s16x8 bh = *(const s16x8*)&whi[2 * 16 * WPAD + brow0 + u * 32];
        s16x8 bl = *(const s16x8*)&wlo[2 * 16 * WPAD + brow0 + u * 32];
        acc2 = __builtin_amdgcn_mfma_f32_16x16x32_bf16(ah, bh, acc2, 0, 0, 0);
        acc2 = __builtin_amdgcn_mfma_f32_16x16x32_bf16(ah, bl, acc2, 0, 0, 0);
        acc2 = __builtin_amdgcn_mfma_f32_16x16x32_bf16(al, bh, acc2, 0, 0, 0);
      }
      {
        s16x8 bh = *(const s16x8*)&whi[3 * 16 * WPAD + brow0 + u * 32];
        s16x8 bl = *(const s16x8*)&wlo[3 * 16 * WPAD + brow0 + u * 32];
        acc3 = __builtin_amdgcn_mfma_f32_16x16x32_bf16(ah, bh, acc3, 0, 0, 0);
        acc3 = __builtin_amdgcn_mfma_f32_16x16x32_bf16(ah, bl, acc3, 0, 0, 0);
        acc3 = __builtin_amdgcn_mfma_f32_16x16x32_bf16(al, bh, acc3, 0, 0, 0);
      }
    }

    // ---- two-stage K-partial reduction in LDS ----
    const int rrow = m * 16 + lk * 4;
    if (ks < 2) {
      #pragma unroll
      for (int r = 0; r < 4; ++r) {
        gates2[ks][0][rrow + r][lm] = acc0[r];
        gates2[ks][1][rrow + r][lm] = acc1[r];
        gates2[ks][2][rrow + r][lm] = acc2[r];
        gates2[ks][3][rrow + r][lm] = acc3[r];
      }
    }
    __syncthreads();
    if (ks >= 2) {
      #pragma unroll
      for (int r = 0; r < 4; ++r) {
        gates2[ks - 2][0][rrow + r][lm] += acc0[r];
        gates2[ks - 2][1][rrow + r][lm] += acc1[r];
        gates2[ks - 2][2][rrow + r][lm] += acc2[r];
        gates2[ks - 2][3][rrow + r][lm] += acc3[r];
      }
    }
    __syncthreads();

    // ---- gate combine ----
    {
      float xv0 = xs[cb][0], xv1 = xs[cb][1], xv2 = xs[cb][2];
      float pre[4];
      #pragma unroll
      for (int qq = 0; qq < 4; ++qq) {
        int r = qq * 16 + cj;
        pre[qq] = gates2[0][qq][cb][cj] + gates2[1][qq][cb][cj] + bsum[r]
                + xv0 * wih_s[r][0] + xv1 * wih_s[r][1] + xv2 * wih_s[r][2];
      }
      float ig = sigm(pre[0]), fg = sigm(pre[1]);
      float gg = tanhx(pre[2]), og = sigm(pre[3]);
      c_state = fg * c_state + ig * gg;
      float hv = og * tanhx(c_state);
      ushort uh = f2bf(hv);
      hstg[cb][cj] = uh;
      lstg[cb][cj] = f2bf(hv - bf2f(uh));
    }
    __syncthreads();

    if (tid < 256) {
      int b = tid >> 3, jp = tid & 7;
      unsigned wh = (unsigned)hstg[b][2 * jp] | ((unsigned)hstg[b][2 * jp + 1] << 16);
      unsigned wl = (unsigned)lstg[b][2 * jp] | ((unsigned)lstg[b][2 * jp + 1] << 16);
      size_t wordo = ((size_t)(cur ^ 1) * Bsz * Hh + (size_t)(b0 + b) * Hh + j0) / 2 + jp;
      __hip_atomic_store((unsigned*)hhi + wordo, wh, __ATOMIC_RELAXED, __HIP_MEMORY_SCOPE_AGENT);
      __hip_atomic_store((unsigned*)hlo + wordo, wl, __ATOMIC_RELAXED, __HIP_MEMORY_SCOPE_AGENT);
    }

    group_barrier(bar, tid, 32u * (t + 2));
    cur ^= 1;
  }

  if (hb == 0) {
    const u64* Hf = (const u64*)(hhi + (size_t)cur * Bsz * Hh);
    const u64* Lf = (const u64*)(hlo + (size_t)cur * Bsz * Hh);
    int b = tid >> 4, lj = tid & 15;
    float p = 0.0f;
    for (int jq = lj; jq < Hh / 4; jq += 16) {
      size_t o = (size_t)(b0 + b) * (Hh / 4) + jq;
      u64 uh = __hip_atomic_load(Hf + o, __ATOMIC_RELAXED, __HIP_MEMORY_SCOPE_AGENT);
      u64 ul = __hip_atomic_load(Lf + o, __ATOMIC_RELAXED, __HIP_MEMORY_SCOPE_AGENT);
      #pragma unroll
      for (int e = 0; e < 4; ++e) {
        float hv = bf2f((ushort)(uh >> (16 * e))) + bf2f((ushort)(ul >> (16 * e)));
        p += hv * fcw[4 * jq + e];
      }
    }
    ((float*)gates2)[tid] = p;
    __syncthreads();
    if (lj == 0) {
      float s = 0.0f;
      #pragma unroll
      for (int r = 0; r < 16; ++r) s += ((float*)gates2)[(b << 4) + r];
      out[b0 + b] = s + fcb[0];
    }
  }
}

extern "C" void kernel_launch(void* const* d_in, const int* in_sizes, int n_in,
                              void* d_out, int out_size, void* d_ws, size_t ws_size,
                              hipStream_t stream) {
  const float* x   = (const float*)d_in[0];
  const float* Wih = (const float*)d_in[1];
  const float* Whh = (const float*)d_in[2];
  const float* bih = (const float*)d_in[3];
  const float* bhh = (const float*)d_in[4];
  const float* fcw = (const float*)d_in[5];
  const float* fcb = (const float*)d_in[6];
  float* out = (float*)d_out;
  char*  ws  = (char*)d_ws;

  hipLaunchKernelGGL(init_ws, dim3(1), dim3(CTRL_UINTS), 0, stream,
                     (unsigned*)(ws + BAR_OFF));
  hipLaunchKernelGGL(lstm_kernel, dim3(NWG), dim3(NTHR), 0, stream,
                     x, Wih, Whh, bih, bhh, fcw, fcb, out, ws);
}